// Round 1
// baseline (351.123 us; speedup 1.0000x reference)
//
#include <hip/hip_runtime.h>
#include <hip/hip_bf16.h>

#define D_IN 128
#define D_OUT 64

// ---------------------------------------------------------------------------
// GEMM: h[n][c] = sum_k x[n][k] * W[c][k] + b[c]
// One wave per node. lane = output channel c. W row held in registers
// (128 VGPRs/lane). x[node][k] is wave-uniform -> scalar loads.
// ---------------------------------------------------------------------------
__global__ void proj_kernel(const float* __restrict__ x,
                            const float* __restrict__ W,
                            const float* __restrict__ b,
                            float* __restrict__ h,
                            int n_nodes) {
    const int lane = threadIdx.x & 63;
    const int wave = (int)((blockIdx.x * blockDim.x + threadIdx.x) >> 6);
    const int nwaves = (int)((gridDim.x * blockDim.x) >> 6);

    // Load this lane's W row into registers (once per wave lifetime).
    float w[D_IN];
#pragma unroll
    for (int k = 0; k < D_IN; k += 4) {
        float4 t = *(const float4*)&W[lane * D_IN + k];
        w[k] = t.x; w[k + 1] = t.y; w[k + 2] = t.z; w[k + 3] = t.w;
    }
    const float bias = b[lane];

    for (int node = wave; node < n_nodes; node += nwaves) {
        // wave-uniform node index -> scalar loads for x
        const int nu = __builtin_amdgcn_readfirstlane(node);
        const float* xr = &x[(size_t)nu * D_IN];
        float acc = bias;
#pragma unroll
        for (int k = 0; k < D_IN; ++k) {
            acc += xr[k] * w[k];
        }
        h[(size_t)nu * D_OUT + lane] = acc;
    }
}

// ---------------------------------------------------------------------------
// Scatter: for each edge e: out[row[e]][:] += h[col[e]][:], deg[row[e]] += 1
// One wave per edge, lane = channel. Coalesced 256B gather per edge.
// ---------------------------------------------------------------------------
__global__ void scatter_kernel(const float* __restrict__ h,
                               const int* __restrict__ row,
                               const int* __restrict__ col,
                               float* __restrict__ out,
                               int* __restrict__ deg,
                               long long n_tasks) {
    long long t = (long long)blockIdx.x * blockDim.x + threadIdx.x;
    const long long stride = (long long)gridDim.x * blockDim.x;
    for (; t < n_tasks; t += stride) {
        const int e = (int)(t >> 6);
        const int c = (int)(t & 63);
        const int r = row[e];   // wave-uniform -> scalar load
        const int s = col[e];   // wave-uniform -> scalar load
        atomicAdd(&out[(size_t)r * D_OUT + c], h[(size_t)s * D_OUT + c]);
        if (c == 0) atomicAdd(&deg[r], 1);
    }
}

// ---------------------------------------------------------------------------
// Divide: out[n][c] /= max(deg[n], 1)
// ---------------------------------------------------------------------------
__global__ void div_kernel(float* __restrict__ out,
                           const int* __restrict__ deg,
                           int n_total) {
    int t = blockIdx.x * blockDim.x + threadIdx.x;
    if (t < n_total) {
        const int node = t >> 6;
        const float d = (float)deg[node];  // wave-uniform -> scalar load
        out[t] = out[t] * (1.0f / fmaxf(d, 1.0f));
    }
}

extern "C" void kernel_launch(void* const* d_in, const int* in_sizes, int n_in,
                              void* d_out, int out_size, void* d_ws, size_t ws_size,
                              hipStream_t stream) {
    const float* x   = (const float*)d_in[0];
    const float* W   = (const float*)d_in[1];
    const float* b   = (const float*)d_in[2];
    const int*   row = (const int*)d_in[3];
    const int*   col = (const int*)d_in[4];
    float* out = (float*)d_out;

    const int n_nodes = in_sizes[0] / D_IN;
    const int n_edges = in_sizes[3];

    // Workspace layout: h [n_nodes * D_OUT floats] | deg [n_nodes ints]
    float* h  = (float*)d_ws;
    int* deg  = (int*)((char*)d_ws + (size_t)n_nodes * D_OUT * sizeof(float));

    // Zero the accumulators (d_out is poisoned 0xAA before every call).
    hipMemsetAsync(d_out, 0, (size_t)out_size * sizeof(float), stream);
    hipMemsetAsync(deg, 0, (size_t)n_nodes * sizeof(int), stream);

    // 1) Projection GEMM
    {
        const int block = 256;
        const int grid = 1024;  // 4096 waves, ~12 nodes each
        proj_kernel<<<grid, block, 0, stream>>>(x, W, b, h, n_nodes);
    }

    // 2) Edge scatter with atomics
    {
        const long long n_tasks = (long long)n_edges * D_OUT;
        const int block = 256;
        const int grid = 16384;
        scatter_kernel<<<grid, block, 0, stream>>>(h, row, col, out, deg, n_tasks);
    }

    // 3) Normalize by degree
    {
        const int n_total = n_nodes * D_OUT;
        const int block = 256;
        const int grid = (n_total + block - 1) / block;
        div_kernel<<<grid, block, 0, stream>>>(out, deg, n_total);
    }
}

// Round 2
// 225.740 us; speedup vs baseline: 1.5554x; 1.5554x over previous
//
#include <hip/hip_runtime.h>
#include <hip/hip_bf16.h>

#define D_IN 128
#define D_OUT 64
#define CAP 64   // per-node bucket capacity; mean degree = 16, P(deg>64) ~ 0

// ---------------------------------------------------------------------------
// GEMM: h[n][c] = sum_k x[n][k] * W[c][k] + b[c]
// One wave per node. lane = output channel c. W row held in registers.
// x[node][k] is wave-uniform -> scalar loads.
// ---------------------------------------------------------------------------
__global__ void proj_kernel(const float* __restrict__ x,
                            const float* __restrict__ W,
                            const float* __restrict__ b,
                            float* __restrict__ h,
                            int n_nodes) {
    const int lane = threadIdx.x & 63;
    const int wave = (int)((blockIdx.x * blockDim.x + threadIdx.x) >> 6);
    const int nwaves = (int)((gridDim.x * blockDim.x) >> 6);

    float w[D_IN];
#pragma unroll
    for (int k = 0; k < D_IN; k += 4) {
        float4 t = *(const float4*)&W[lane * D_IN + k];
        w[k] = t.x; w[k + 1] = t.y; w[k + 2] = t.z; w[k + 3] = t.w;
    }
    const float bias = b[lane];

    for (int node = wave; node < n_nodes; node += nwaves) {
        const int nu = __builtin_amdgcn_readfirstlane(node);
        const float* xr = &x[(size_t)nu * D_IN];
        float acc = bias;
#pragma unroll
        for (int k = 0; k < D_IN; ++k) {
            acc += xr[k] * w[k];
        }
        h[(size_t)nu * D_OUT + lane] = acc;
    }
}

// ---------------------------------------------------------------------------
// Bucket build: thread per edge. deg[row]++ (int atomic); place col into
// bucket[row*CAP + p]; overflow edges (p >= CAP) go to an overflow list.
// ---------------------------------------------------------------------------
__global__ void bucket_kernel(const int* __restrict__ row,
                              const int* __restrict__ col,
                              int* __restrict__ deg,
                              int* __restrict__ bucket,
                              int* __restrict__ ovf_cnt,
                              int* __restrict__ ovf_list,
                              int ovf_cap,
                              int n_edges) {
    int e = blockIdx.x * blockDim.x + threadIdx.x;
    if (e >= n_edges) return;
    const int r = row[e];
    const int c = col[e];
    const int p = atomicAdd(&deg[r], 1);
    if (p < CAP) {
        bucket[(size_t)r * CAP + p] = c;
    } else {
        const int idx = atomicAdd(ovf_cnt, 1);
        if (idx < ovf_cap) ovf_list[idx] = e;
    }
}

// ---------------------------------------------------------------------------
// Gather: one wave per node. Lanes cooperatively read the node's bucket
// (lane i holds edge i's col), broadcast via shfl, accumulate h rows in
// registers. Writes the RAW SUM (division happens in div_kernel).
// ---------------------------------------------------------------------------
__global__ void gather_kernel(const float* __restrict__ h,
                              const int* __restrict__ deg,
                              const int* __restrict__ bucket,
                              float* __restrict__ out,
                              int n_nodes) {
    const int lane = threadIdx.x & 63;
    int wave = (int)((blockIdx.x * blockDim.x + threadIdx.x) >> 6);
    const int nwaves = (int)((gridDim.x * blockDim.x) >> 6);

    for (int node = wave; node < n_nodes; node += nwaves) {
        const int d = deg[node];                 // wave-uniform
        const int dc = d < CAP ? d : CAP;
        const int mycol = (lane < dc) ? bucket[(size_t)node * CAP + lane] : 0;
        float a0 = 0.f, a1 = 0.f, a2 = 0.f, a3 = 0.f;
        int i = 0;
        for (; i + 4 <= dc; i += 4) {
            const int c0 = __shfl(mycol, i);
            const int c1 = __shfl(mycol, i + 1);
            const int c2 = __shfl(mycol, i + 2);
            const int c3 = __shfl(mycol, i + 3);
            a0 += h[(size_t)c0 * D_OUT + lane];
            a1 += h[(size_t)c1 * D_OUT + lane];
            a2 += h[(size_t)c2 * D_OUT + lane];
            a3 += h[(size_t)c3 * D_OUT + lane];
        }
        for (; i < dc; ++i) {
            const int c = __shfl(mycol, i);
            a0 += h[(size_t)c * D_OUT + lane];
        }
        out[(size_t)node * D_OUT + lane] = (a0 + a1) + (a2 + a3);
    }
}

// ---------------------------------------------------------------------------
// Overflow apply: wave per overflow edge, atomicAdd into out (raw sums).
// With CAP=64 the count is 0 and this is a no-op launch.
// ---------------------------------------------------------------------------
__global__ void ovf_apply_kernel(const float* __restrict__ h,
                                 const int* __restrict__ row,
                                 const int* __restrict__ col,
                                 const int* __restrict__ ovf_list,
                                 const int* __restrict__ ovf_cnt,
                                 float* __restrict__ out,
                                 int ovf_cap) {
    const int cnt = *ovf_cnt < ovf_cap ? *ovf_cnt : ovf_cap;
    const long long n_tasks = (long long)cnt * D_OUT;
    long long t = (long long)blockIdx.x * blockDim.x + threadIdx.x;
    const long long stride = (long long)gridDim.x * blockDim.x;
    for (; t < n_tasks; t += stride) {
        const int k = (int)(t >> 6);
        const int lane = (int)(t & 63);
        const int e = ovf_list[k];
        const int r = row[e];
        const int s = col[e];
        atomicAdd(&out[(size_t)r * D_OUT + lane], h[(size_t)s * D_OUT + lane]);
    }
}

// ---------------------------------------------------------------------------
// Divide: out[n][c] /= max(deg[n], 1)
// ---------------------------------------------------------------------------
__global__ void div_kernel(float* __restrict__ out,
                           const int* __restrict__ deg,
                           int n_total) {
    int t = blockIdx.x * blockDim.x + threadIdx.x;
    if (t < n_total) {
        const int node = t >> 6;
        const float d = (float)deg[node];
        out[t] = out[t] * (1.0f / fmaxf(d, 1.0f));
    }
}

// ---------------------------------------------------------------------------
// Fallback scatter (old path) if ws is too small for buckets.
// ---------------------------------------------------------------------------
__global__ void scatter_kernel(const float* __restrict__ h,
                               const int* __restrict__ row,
                               const int* __restrict__ col,
                               float* __restrict__ out,
                               int* __restrict__ deg,
                               long long n_tasks) {
    long long t = (long long)blockIdx.x * blockDim.x + threadIdx.x;
    const long long stride = (long long)gridDim.x * blockDim.x;
    for (; t < n_tasks; t += stride) {
        const int e = (int)(t >> 6);
        const int c = (int)(t & 63);
        const int r = row[e];
        const int s = col[e];
        atomicAdd(&out[(size_t)r * D_OUT + c], h[(size_t)s * D_OUT + c]);
        if (c == 0) atomicAdd(&deg[r], 1);
    }
}

extern "C" void kernel_launch(void* const* d_in, const int* in_sizes, int n_in,
                              void* d_out, int out_size, void* d_ws, size_t ws_size,
                              hipStream_t stream) {
    const float* x   = (const float*)d_in[0];
    const float* W   = (const float*)d_in[1];
    const float* b   = (const float*)d_in[2];
    const int*   row = (const int*)d_in[3];
    const int*   col = (const int*)d_in[4];
    float* out = (float*)d_out;

    const int n_nodes = in_sizes[0] / D_IN;
    const int n_edges = in_sizes[3];

    // Workspace layout:
    //   h        [n_nodes * D_OUT floats]
    //   deg      [n_nodes ints]
    //   ovf_cnt  [64 ints (padding for alignment)]
    //   ovf_list [n_edges ints]
    //   bucket   [n_nodes * CAP ints]
    char* p = (char*)d_ws;
    float* h = (float*)p;              p += (size_t)n_nodes * D_OUT * sizeof(float);
    int* deg = (int*)p;                p += (size_t)n_nodes * sizeof(int);
    int* ovf_cnt = (int*)p;            p += 64 * sizeof(int);
    int* ovf_list = (int*)p;           p += (size_t)n_edges * sizeof(int);
    int* bucket = (int*)p;             p += (size_t)n_nodes * CAP * sizeof(int);
    const size_t needed = (size_t)(p - (char*)d_ws);

    // 1) Projection GEMM (common to both paths)
    proj_kernel<<<1024, 256, 0, stream>>>(x, W, b, h, n_nodes);

    if (ws_size >= needed) {
        // ---- bucketed pull path (no fp32 atomics in the common case) ----
        hipMemsetAsync(deg, 0, (size_t)n_nodes * sizeof(int), stream);
        hipMemsetAsync(ovf_cnt, 0, 64 * sizeof(int), stream);

        bucket_kernel<<<(n_edges + 255) / 256, 256, 0, stream>>>(
            row, col, deg, bucket, ovf_cnt, ovf_list, n_edges, n_edges);

        const int n_waves_total = n_nodes;  // one wave per node
        const int grid = (n_waves_total * 64 + 255) / 256;
        gather_kernel<<<grid, 256, 0, stream>>>(h, deg, bucket, out, n_nodes);

        ovf_apply_kernel<<<256, 256, 0, stream>>>(h, row, col, ovf_list, ovf_cnt,
                                                  out, n_edges);

        const int n_total = n_nodes * D_OUT;
        div_kernel<<<(n_total + 255) / 256, 256, 0, stream>>>(out, deg, n_total);
    } else {
        // ---- fallback: atomic scatter (round-1 path) ----
        hipMemsetAsync(out, 0, (size_t)out_size * sizeof(float), stream);
        hipMemsetAsync(deg, 0, (size_t)n_nodes * sizeof(int), stream);
        const long long n_tasks = (long long)n_edges * D_OUT;
        scatter_kernel<<<16384, 256, 0, stream>>>(h, row, col, out, deg, n_tasks);
        const int n_total = n_nodes * D_OUT;
        div_kernel<<<(n_total + 255) / 256, 256, 0, stream>>>(out, deg, n_total);
    }
}